// Round 6
// baseline (117.507 us; speedup 1.0000x reference)
//
#include <hip/hip_runtime.h>
#include <math.h>

// Highpass biquad: FIR(b0,b1,b2) + IIR(a1,a2) recurrence, clamp [-1,1].
// R14: register-staging build. R13 post-mortem: pipeline+locality -> 29.2us
// kernel (4.4 TB/s), but R9/R11/R12/R13 (burst/pipelined, 4-10 waves/CU)
// ALL wall at ~4.2-4.4 TB/s vs 6.29 TB/s copy ceiling. Structural
// invariants across all four: (a) global_load_lds DMA carries 100% of the
// read stream (copy ubench uses register loads; DMA path never validated
// at full streaming rate - suspected per-CU outstanding-transaction limit),
// (b) residency capped at 4-5 waves/CU by the 32KB LDS ping-pong.
// Fix both at once: REGISTER staging (global_load_dwordx4 -> VGPR ->
// swizzled ds_write_b128). The second buffer IS the register file ->
// single 16KB LDS buffer, SPB=2, 2048 blocks = 8 waves/CU (2x residency),
// still 1-deep pipelined: both segments' 16 loads issue at block start
// (sched_barrier pins them); seg1's loads fly under seg0's ~1540cyc
// compute. No inline-asm waits: register dests make the dataflow visible,
// compiler emits minimal COUNTED vmcnt itself (never 0: NT stores of the
// previous segment are newest in the queue). DS-pipe program order makes
// ds_write(seg1) safe after seg0's store-phase ds_reads without any wait.
// Kept from R12/R13 (proven): bijective XCD swizzle (2048%8==0, each XCD
// owns a contiguous 16MB slice), NT stores (dead output lines bypass
// L2/L3), XOR-swizzled LDS slot(r,p')=16r|(p'^(r&15)) - bank-quad
// balanced in EVERY phase (ds_write per instr: 4 rows x 16 cols, each
// quad 8 lanes; warmup/main/store reads likewise), all ds traffic b128.
// Now applied directly on the write side (no DMA -> no inverse-source).
// Segment chaining (HW-verified R13, absmax 3.9e-3): lane 63's
// (y1,y2,p1,p2) after main of seg0 is the EXACT state at seg1's base ->
// __shfl to lane 0 (skips warmup) and lane 1 (exact FIR ICs).
// In-place main over row tid safe in a single wave (in-order DS pipe).
// No barriers anywhere (1-wave blocks). 16KB LDS -> LDS allows 10
// blocks/CU; grid 2048 = 8/CU resident.
// Coefficients in float (HW v_sin/v_cos): err ~1e-7 << absmax 3.9e-3,
// threshold 1.06e-2. Warmup length 64: boundary err 0.904^64 ~ 1.6e-3.

constexpr int T_LEN  = 131072;
constexpr int L      = 64;               // samples per chunk (= per thread)
constexpr int CPB    = 64;               // chunks per segment = 1 wave
constexpr int SEG    = CPB * L;          // 4096 floats per segment
constexpr int SPB    = 2;                // segments per block (pipelined)
constexpr int GRP_PER_SEQ = T_LEN / (SEG * SPB); // 16
constexpr int NSEQ   = 64 * 2;           // 128 sequences
constexpr int NBLOCKS = NSEQ * GRP_PER_SEQ;      // 2048 (divisible by 8)

typedef float fx4 __attribute__((ext_vector_type(4)));

__global__ __launch_bounds__(64) void hp_kernel(
    const float* __restrict__ x,
    const float* __restrict__ pfreq,
    const float* __restrict__ pq,
    float* __restrict__ out)
{
    __shared__ fx4 lds4[CPB * 16];       // 64 rows x 16 f4 = 16384 B

    // --- coefficients (float; HW trig) ---
    float freq = fminf(fmaxf(pfreq[0], 100.0f), 44100.0f * 0.5f - 1.0f);
    float q    = fminf(fmaxf(pq[0], 0.1f), 10.0f);
    float w0   = 2.0f * (float)M_PI * freq / 44100.0f;
    float cw   = cosf(w0);
    float alpha = sinf(w0) / (2.0f * q);
    float ia0  = 1.0f / (1.0f + alpha);
    const float b0 = (1.0f + cw) * 0.5f * ia0;
    const float b1 = -(1.0f + cw) * ia0;
    const float b2 = b0;
    const float a1 = -2.0f * cw * ia0;
    const float a2 = (1.0f - alpha) * ia0;

    // bijective XCD swizzle: XCD x owns orig-blocks [x*256,(x+1)*256) =
    // a contiguous ~16MB slice of input+output.
    const int borig = blockIdx.x;
    const int b     = ((borig & 7) << 8) | (borig >> 3);

    const int seq = b >> 4;              // / GRP_PER_SEQ
    const int S0  = (b & (GRP_PER_SEQ - 1)) * (SEG * SPB);
    const float* __restrict__ xs = x   + (size_t)seq * T_LEN;
    float*       __restrict__ os = out + (size_t)seq * T_LEN;
    const int tid = threadIdx.x;

    // --- prologue: issue ALL global loads up front (pipeline). Lane tid
    // loads f4 index tid+64k of each segment (coalesced); seg1's 16KB
    // flies under seg0's compute. ---
    const fx4* g0 = (const fx4*)(xs + S0);
    fx4 a[16], bb[16];
#pragma unroll
    for (int k = 0; k < 16; ++k) a[k]  = g0[tid + (k << 6)];
#pragma unroll
    for (int k = 0; k < 16; ++k) bb[k] = g0[1024 + tid + (k << 6)];

    // seg0 head state (prev group tail), register dests, exec-masked:
    float hp1 = 0.f, hp2 = 0.f;
    if (S0 > 0 && tid < 2) {
        const float* w = xs + S0 + (tid - 1) * L;
        hp1 = w[-1]; hp2 = w[-2];
    }
    fx4 h[16];
    if (S0 > 0 && tid == 0) {
        const fx4* gw = (const fx4*)(xs + S0 - L);
#pragma unroll
        for (int k = 0; k < 16; ++k) h[k] = gw[k];
    }
    __builtin_amdgcn_sched_barrier(0);   // pin load issue above compute

    // y = (xf - a2*y2) - a1*y1 => critical path y1->y is one FMA (~4cyc)
#define STEP(xv) { \
        float xf_ = fmaf(b2, p2, fmaf(b1, p1, b0 * (xv))); \
        float yv  = fmaf(-a1, y1, fmaf(-a2, y2, xf_)); \
        p2 = p1; p1 = (xv); y2 = y1; y1 = yv; }

    // chained exact state from lane 63 (set after seg0)
    float ny1, ny2, np1, np2;

    // ================= segment 0 =================
    {
        // ds_write seg0: lane's f4 g=tid+64k -> swizzled slot
        // (compiler inserts counted vmcnt for a[] here)
#pragma unroll
        for (int k = 0; k < 16; ++k) {
            int g = tid + (k << 6);
            int r = g >> 4;
            lds4[(r << 4) | ((g & 15) ^ (r & 15))] = a[k];
        }

        float y1 = 0.f, y2 = 0.f, p1 = 0.f, p2 = 0.f;

        // --- warmup: thread t converges over chunk cgm-1 ---
        const int cgm = (S0 >> 6) + tid;
        if (cgm >= 1) {
            if (cgm >= 2) {
                if (tid >= 2) {              // tail of chunk cgm-2 in LDS
                    int rr = tid - 2;
                    const float* pr = (const float*)
                        (lds4 + ((rr << 4) | (15 ^ (rr & 15))));
                    p2 = pr[2]; p1 = pr[3];
                } else { p1 = hp1; p2 = hp2; }
            }                                // cgm==1: zero ICs (exact)
            const fx4* rp = lds4 + (((tid - 1) & 63) << 4);
            const int  xr = (tid - 1) & 15;
#pragma unroll
            for (int j4 = 0; j4 < 16; ++j4) {
                fx4 v = (tid == 0) ? h[j4] : rp[j4 ^ xr];
                STEP(v.x); STEP(v.y); STEP(v.z); STEP(v.w);
            }
        }
        // cgm==0: exact zero ICs (matches reference padding)

        // --- main: in-place over row tid (safe: in-order single wave) ---
        {
            fx4* mrow = lds4 + (tid << 4);
            const int xm = tid & 15;
#pragma unroll
            for (int j4 = 0; j4 < 16; ++j4) {
                int idx = j4 ^ xm;
                fx4 v = mrow[idx];
                fx4 o;
                STEP(v.x); o.x = fminf(fmaxf(y1, -1.f), 1.f);
                STEP(v.y); o.y = fminf(fmaxf(y1, -1.f), 1.f);
                STEP(v.z); o.z = fminf(fmaxf(y1, -1.f), 1.f);
                STEP(v.w); o.w = fminf(fmaxf(y1, -1.f), 1.f);
                mrow[idx] = o;
            }
        }

        // exact end-state of the group's first 4096 samples -> seg1
        ny1 = __shfl(y1, 63); ny2 = __shfl(y2, 63);
        np1 = __shfl(p1, 63); np2 = __shfl(p2, 63);

        // --- coalesced NT store of seg0 ---
        {
            fx4* ob = (fx4*)(os + S0);
#pragma unroll
            for (int k = 0; k < 16; ++k) {
                int f = tid + (k << 6);
                int r = f >> 4;
                fx4 v = lds4[(r << 4) | ((f & 15) ^ (r & 15))];
                __builtin_nontemporal_store(v, &ob[f]);
            }
        }
    }

    // ================= segment 1 =================
    {
        // ds_write seg1: DS pipe is in-order per wave -> these land after
        // seg0's store-phase ds_reads; compiler's vmcnt wait for bb[] is
        // counted (16 NT stores are newer in the queue).
#pragma unroll
        for (int k = 0; k < 16; ++k) {
            int g = tid + (k << 6);
            int r = g >> 4;
            lds4[(r << 4) | ((g & 15) ^ (r & 15))] = bb[k];
        }

        float y1, y2, p1, p2;
        if (tid == 0) {                      // exact chained state
            y1 = ny1; y2 = ny2; p1 = np1; p2 = np2;
        } else {
            y1 = 0.f; y2 = 0.f;
            if (tid >= 2) {                  // tail of row tid-2 (this seg)
                int rr = tid - 2;
                const float* pr = (const float*)
                    (lds4 + ((rr << 4) | (15 ^ (rr & 15))));
                p2 = pr[2]; p1 = pr[3];
            } else { p1 = np1; p2 = np2; }   // tid==1: exact via shfl
            const fx4* rp = lds4 + ((tid - 1) << 4);
            const int  xr = (tid - 1) & 15;
#pragma unroll
            for (int j4 = 0; j4 < 16; ++j4) {
                fx4 v = rp[j4 ^ xr];
                STEP(v.x); STEP(v.y); STEP(v.z); STEP(v.w);
            }
        }

        // --- main: in-place over row tid ---
        {
            fx4* mrow = lds4 + (tid << 4);
            const int xm = tid & 15;
#pragma unroll
            for (int j4 = 0; j4 < 16; ++j4) {
                int idx = j4 ^ xm;
                fx4 v = mrow[idx];
                fx4 o;
                STEP(v.x); o.x = fminf(fmaxf(y1, -1.f), 1.f);
                STEP(v.y); o.y = fminf(fmaxf(y1, -1.f), 1.f);
                STEP(v.z); o.z = fminf(fmaxf(y1, -1.f), 1.f);
                STEP(v.w); o.w = fminf(fmaxf(y1, -1.f), 1.f);
                mrow[idx] = o;
            }
        }

        // --- coalesced NT store of seg1 ---
        {
            fx4* ob = (fx4*)(os + S0 + SEG);
#pragma unroll
            for (int k = 0; k < 16; ++k) {
                int f = tid + (k << 6);
                int r = f >> 4;
                fx4 v = lds4[(r << 4) | ((f & 15) ^ (r & 15))];
                __builtin_nontemporal_store(v, &ob[f]);
            }
        }
    }
#undef STEP
}

extern "C" void kernel_launch(void* const* d_in, const int* in_sizes, int n_in,
                              void* d_out, int out_size, void* d_ws, size_t ws_size,
                              hipStream_t stream) {
    const float* x  = (const float*)d_in[0];
    // d_in[1] = t, unused by the reference computation
    const float* ff = (const float*)d_in[2];
    const float* fq = (const float*)d_in[3];
    float* out = (float*)d_out;
    hp_kernel<<<NBLOCKS, CPB, 0, stream>>>(x, ff, fq, out);
}